// Round 1
// 132.657 us; speedup vs baseline: 1.0692x; 1.0692x over previous
//
#include <hip/hip_runtime.h>

#define CANVAS 512
#define PLANE (CANVAS * CANVAS)   // 262144 cells per batch (2^18)
#define WORDS (PLANE / 32)        // 8192 words per batch, bit-packed
#define GRIDW 513                 // wrap modulus (pseudo_image_dims + 1)
#define BATCH 2
#define N_LI 1000000
#define N_RA 500000

typedef int int2v __attribute__((ext_vector_type(2)));
typedef int int4v __attribute__((ext_vector_type(4)));

// ---------------------------------------------------------------------------
// Kernel 1: zero the dyn byte plane (workspace is poisoned 0xAA before call).
// neigh word-plane needs no zeroing: dilate writes every word.
__global__ void zero_dyn(uint32_t* __restrict__ p, int nwords) {
    int i = blockIdx.x * blockDim.x + threadIdx.x;
    if (i < nwords) p[i] = 0u;
}

// ---------------------------------------------------------------------------
// Kernel 2: ra points, 2 points/thread. Write ra_dy / ra_ind (int2 stores),
// scatter dyn flags as benign-race byte stores (OR semantics: max|vr|>0.1
// == OR of per-point |vr|>0.1).
__global__ __launch_bounds__(256) void ra_kernel(
        const float* __restrict__ ra_input,
        const int*   __restrict__ ra_coords,
        int* __restrict__ ra_dy_out,
        int* __restrict__ ra_ind_out,
        unsigned char* __restrict__ dyn) {
    int i = blockIdx.x * blockDim.x + threadIdx.x;
    if (i >= BATCH * N_RA / 2) return;
    // coords layout per point: (y, x)
    int4v c = __builtin_nontemporal_load((const int4v*)ra_coords + i);
    float vr0 = fabsf(__builtin_nontemporal_load(ra_input + (size_t)i * 10 + 4));
    float vr1 = fabsf(__builtin_nontemporal_load(ra_input + (size_t)i * 10 + 9));
    int flat0 = c.x * CANVAS + c.y;
    int flat1 = c.z * CANVAS + c.w;
    int dy0 = vr0 > 0.1f ? 1 : 0;
    int dy1 = vr1 > 0.1f ? 1 : 0;

    int2v dyv;  dyv.x = dy0;   dyv.y = dy1;
    int2v indv; indv.x = flat0; indv.y = flat1;
    __builtin_nontemporal_store(dyv,  (int2v*)ra_dy_out + i);
    __builtin_nontemporal_store(indv, (int2v*)ra_ind_out + i);

    int b = i / (N_RA / 2);            // pairs never straddle batches (N_RA even)
    unsigned char* db = dyn + (size_t)b * PLANE;
    if (dy0) db[flat0] = 1;
    if (dy1) db[flat1] = 1;
}

// ---------------------------------------------------------------------------
// Kernel 3: 5x5 dilation with the reference's mod-513 wrap quirk.
// Inverse per target cell t: src = (t - off) mod 513, valid iff src < 512.
// Fully unrolled, branchless (no runtime-indexed private arrays -> no
// scratch). Output is BIT-PACKED via wave ballot: a wave covers 64
// consecutive x of one row (grid is exact, PLANE % 256 == 0, no tail).
__global__ __launch_bounds__(256) void dilate_kernel(
        const unsigned char* __restrict__ dyn,
        uint32_t* __restrict__ neighw) {
    int idx  = blockIdx.x * blockDim.x + threadIdx.x;   // 0 .. B*PLANE-1 exact
    int b    = idx >> 18;                               // / PLANE
    int cell = idx & (PLANE - 1);
    int ty = cell >> 9;
    int tx = cell & (CANVAS - 1);
    const unsigned char* d = dyn + (size_t)b * PLANE;

    int acc = 0;
#pragma unroll
    for (int off = -2; off <= 2; ++off) {
        int sy = ty - off;
        sy += (sy < 0)      ? GRIDW : 0;
        sy -= (sy >= GRIDW) ? GRIDW : 0;        // 513 wraps to 0
        bool vy = (sy < CANVAS);                // 512 row is dropped
        int rowbase = (vy ? sy : 0) * CANVAS;   // safe clamped address
#pragma unroll
        for (int off2 = -2; off2 <= 2; ++off2) {
            int sx = tx - off2;
            sx += (sx < 0)      ? GRIDW : 0;
            sx -= (sx >= GRIDW) ? GRIDW : 0;
            bool vx = (sx < CANVAS);
            int v = d[rowbase + (vx ? sx : 0)];
            acc |= (vy && vx) ? v : 0;
        }
    }
    unsigned long long m = __ballot(acc != 0);
    int lane = threadIdx.x & 63;
    if (lane == 0)       neighw[idx >> 5] = (uint32_t)m;
    else if (lane == 32) neighw[idx >> 5] = (uint32_t)(m >> 32);
}

// ---------------------------------------------------------------------------
// Kernel 4: li points, 2 points/thread. li_ind = flat index; li_dy = bit
// gather from the 32 KB/batch packed neigh plane (L1-resident).
__global__ __launch_bounds__(256) void li_kernel(
        const int* __restrict__ li_coords,
        const uint32_t* __restrict__ neighw,
        int* __restrict__ li_dy_out,
        int* __restrict__ li_ind_out) {
    int i = blockIdx.x * blockDim.x + threadIdx.x;
    if (i >= BATCH * N_LI / 2) return;
    int4v c = __builtin_nontemporal_load((const int4v*)li_coords + i);
    int flat0 = c.x * CANVAS + c.y;
    int flat1 = c.z * CANVAS + c.w;
    int b = i / (N_LI / 2);            // pairs never straddle batches (N_LI even)
    const uint32_t* nb = neighw + (size_t)b * WORDS;
    uint32_t w0 = nb[flat0 >> 5];
    uint32_t w1 = nb[flat1 >> 5];
    int2v dyv;
    dyv.x = (int)((w0 >> (flat0 & 31)) & 1u);
    dyv.y = (int)((w1 >> (flat1 & 31)) & 1u);
    int2v indv; indv.x = flat0; indv.y = flat1;
    __builtin_nontemporal_store(indv, (int2v*)li_ind_out + i);
    __builtin_nontemporal_store(dyv,  (int2v*)li_dy_out + i);
}

// ---------------------------------------------------------------------------
extern "C" void kernel_launch(void* const* d_in, const int* in_sizes, int n_in,
                              void* d_out, int out_size, void* d_ws, size_t ws_size,
                              hipStream_t stream) {
    // inputs (setup_inputs order):
    // 0: li_input  (B,N_LI,4) f32   -- unused (shape-only in reference)
    // 1: li_coords (B,N_LI,2) i32
    // 2: li_point_idxes              -- identity, unused
    // 3: ra_input  (B,N_RA,5) f32   -- only column 4 used
    // 4: ra_coords (B,N_RA,2) i32
    // 5: ra_point_idxes              -- identity, unused
    const int*   li_coords = (const int*)d_in[1];
    const float* ra_input  = (const float*)d_in[3];
    const int*   ra_coords = (const int*)d_in[4];

    // outputs concatenated in return order, promoted dtype int32:
    // li_dy (B,N_LI), li_ind (B,N_LI), ra_dy (B,N_RA), ra_ind (B,N_RA)
    int* out        = (int*)d_out;
    int* li_dy_out  = out;
    int* li_ind_out = out + (size_t)BATCH * N_LI;
    int* ra_dy_out  = out + (size_t)2 * BATCH * N_LI;
    int* ra_ind_out = out + (size_t)2 * BATCH * N_LI + (size_t)BATCH * N_RA;

    unsigned char* dyn    = (unsigned char*)d_ws;              // B*PLANE bytes
    uint32_t*      neighw = (uint32_t*)(dyn + (size_t)BATCH * PLANE); // B*WORDS words

    const int nwords = BATCH * PLANE / 4;
    zero_dyn<<<(nwords + 255) / 256, 256, 0, stream>>>((uint32_t*)dyn, nwords);

    const int ra_pairs = BATCH * N_RA / 2;
    ra_kernel<<<(ra_pairs + 255) / 256, 256, 0, stream>>>(
        ra_input, ra_coords, ra_dy_out, ra_ind_out, dyn);

    dilate_kernel<<<BATCH * PLANE / 256, 256, 0, stream>>>(dyn, neighw);

    const int li_pairs = BATCH * N_LI / 2;
    li_kernel<<<(li_pairs + 255) / 256, 256, 0, stream>>>(
        li_coords, neighw, li_dy_out, li_ind_out);
}